// Round 7
// baseline (51.815 us; speedup 1.0000x reference)
//
#include <hip/hip_runtime.h>

#define Bn 512
#define BC 32   // b rows per block
#define JT 16   // j columns per block

// sigmoid((sk - sj)/tau) = 1 / (1 + exp2(tj - tk)), t = s * log2(e)/tau
__device__ __forceinline__ float sigterm(float tj, float tk) {
    float e = __builtin_amdgcn_exp2f(tj - tk);
    return __builtin_amdgcn_rcpf(1.0f + e);
}

__global__ __launch_bounds__(1024, 8) void srap_main(
        const float* __restrict__ scores,
        const float* __restrict__ target,
        float* __restrict__ wsC,
        float* __restrict__ wsT) {
    // scores chunk transposed+packed+swizzled:
    // granule g(k4,b) = k4*32 + (b ^ (k4&31)) holds scores[b0+b][4k4..4k4+3]*C
    __shared__ __align__(16) float sT[(Bn / 4) * BC * 4];   // 64 KB
    __shared__ float pA[512], pP[512];
    __shared__ float partC[8 * 32], partT[8 * 32];

    const int tid = threadIdx.x;          // 0..1023
    const int b0 = blockIdx.x * BC;
    const int j0 = blockIdx.y * JT;
    const int jl = (tid >> 5) & (JT - 1); // local j (0..15)
    const int bl = tid & 31;              // local b (0..31)
    const int h  = tid >> 9;              // k-half (0,1)

    const float C = 144.26950408889634f;  // log2(e)/tau, tau = 0.01

    // ---- stage scores[b0..b0+31][0..511]*C -> sT (transposed, swizzled) ----
    {
        const int sr = tid >> 5;          // staged b-row 0..31
        const int sk = tid & 31;          // low k4 bits
        const float4* g4 = (const float4*)(scores + (size_t)(b0 + sr) * Bn);
        #pragma unroll
        for (int i = 0; i < 4; ++i) {
            const int k4 = sk + i * 32;
            float4 v = g4[k4];
            v.x *= C; v.y *= C; v.z *= C; v.w *= C;
            const int g = k4 * BC + (sr ^ (k4 & 31));
            *(float4*)(&sT[g * 4]) = v;
        }
    }
    __syncthreads();

    const int j = j0 + jl;
    const float tj = scores[(size_t)(b0 + bl) * Bn + j] * C;
    const float4* __restrict__ trow = (const float4*)(target + (size_t)j * Bn);

    float A0 = 0.0f, A1 = 0.0f;  // sum_k sigmoid (split chains)
    float P  = 0.0f;             // sum_k sigmoid * target[j,k]

    const int kb = h * (Bn / 8); // 64 float4 iterations per half
    #pragma unroll 4
    for (int k4 = kb; k4 < kb + Bn / 8; ++k4) {
        const float4 w = trow[k4];            // 2 distinct addrs/wave (L1/L2)
        const int g = k4 * BC + (bl ^ (k4 & 31));
        const float4 tk = *(const float4*)(&sT[g * 4]);

        float s0 = sigterm(tj, tk.x);
        float s1 = sigterm(tj, tk.y);
        float s2 = sigterm(tj, tk.z);
        float s3 = sigterm(tj, tk.w);
        A0 += s0 + s1;
        A1 += s2 + s3;
        P = fmaf(s0, w.x, P);
        P = fmaf(s1, w.y, P);
        P = fmaf(s2, w.z, P);
        P = fmaf(s3, w.w, P);
    }
    const float A = A0 + A1;

    // merge k-halves through LDS (A,P are linear in k)
    if (h == 1) { pA[tid & 511] = A; pP[tid & 511] = P; }
    __syncthreads();

    float c = 0.0f, tt = 0.0f;
    if (h == 0) {
        // diag k=j gives exactly 0.5 to A and P (tgt[j,j]=1):
        // sim_all = A_full + 0.5; pos = P_full - 0.5 + target[b,j]
        const float Af  = A + pA[tid] + 0.5f;
        const float tbj = target[(size_t)(b0 + bl) * Bn + j];
        const float Pf  = P + pP[tid] - 0.5f + tbj;
        c  = (Pf * tbj) / Af;
        tt = tbj;
    }

    // reduce over the block's 16 j per b: waves 0..7 hold h=0
    float c2 = c + __shfl_down(c, 32);
    float t2 = tt + __shfl_down(tt, 32);
    const int wv = tid >> 6;
    if (h == 0 && (tid & 63) < 32) { partC[wv * 32 + bl] = c2; partT[wv * 32 + bl] = t2; }
    __syncthreads();

    if (tid < BC) {
        float cs = 0.0f, ts = 0.0f;
        #pragma unroll
        for (int w2 = 0; w2 < 8; ++w2) { cs += partC[w2 * 32 + tid]; ts += partT[w2 * 32 + tid]; }
        wsC[(size_t)blockIdx.y * Bn + b0 + tid] = cs;
        wsT[(size_t)blockIdx.y * Bn + b0 + tid] = ts;
    }
}

__global__ __launch_bounds__(512) void srap_final(
        const float* __restrict__ wsC, const float* __restrict__ wsT,
        float* __restrict__ out) {
    __shared__ float red[8];
    const int b = threadIdx.x;  // 512 threads, one per batch row
    float num = 0.0f, den = 0.0f;
    #pragma unroll
    for (int jt = 0; jt < Bn / JT; ++jt) {
        num += wsC[jt * Bn + b];
        den += wsT[jt * Bn + b];
    }
    float apb = num / den;
    for (int off = 32; off; off >>= 1) apb += __shfl_down(apb, off);
    if ((b & 63) == 0) red[b >> 6] = apb;
    __syncthreads();
    if (b == 0) {
        float s = 0.0f;
        #pragma unroll
        for (int w = 0; w < 8; ++w) s += red[w];
        out[0] = 1.0f - s * (1.0f / Bn);
    }
}

extern "C" void kernel_launch(void* const* d_in, const int* in_sizes, int n_in,
                              void* d_out, int out_size, void* d_ws, size_t ws_size,
                              hipStream_t stream) {
    const float* scores = (const float*)d_in[0];
    const float* target = (const float*)d_in[1];
    float* out = (float*)d_out;
    float* wsC = (float*)d_ws;                       // 32*512 floats
    float* wsT = wsC + (Bn / JT) * Bn;               // 32*512 floats

    srap_main<<<dim3(Bn / BC, Bn / JT), dim3(1024), 0, stream>>>(scores, target, wsC, wsT);
    srap_final<<<dim3(1), dim3(512), 0, stream>>>(wsC, wsT, out);
}

// Round 8
// 39.328 us; speedup vs baseline: 1.3175x; 1.3175x over previous
//
#include <hip/hip_runtime.h>

#define Bn 512
#define BC 16   // b rows per block
#define JT 32   // j columns per block
// block: 512 threads = 16 bl x 32 jl, one (b,j) pair per thread
// grid (32, 16) = 512 blocks, LDS 34 KB -> 4 blocks/CU = 32 waves/CU

// sigmoid((sk - sj)/tau) = 1 / (1 + exp2(tj - tk)), t = s * log2(e)/tau
__device__ __forceinline__ float sigterm(float tj, float tk) {
    float e = __builtin_amdgcn_exp2f(tj - tk);
    return __builtin_amdgcn_rcpf(1.0f + e);
}

__global__ __launch_bounds__(512, 8) void srap_main(
        const float* __restrict__ scores,
        const float* __restrict__ target,
        float* __restrict__ wsC,
        float* __restrict__ wsT) {
    // scores chunk transposed+packed+swizzled:
    // granule g(k4,b) = k4*16 + (b ^ (k4&15)) holds scores[b0+b][4k4..4k4+3]*C
    __shared__ __align__(16) float sT[(Bn / 4) * BC * 4];   // 32 KB
    __shared__ float partC[8 * BC], partT[8 * BC];

    const int tid = threadIdx.x;          // 0..511
    const int b0 = blockIdx.x * BC;
    const int j0 = blockIdx.y * JT;
    const int jl = tid >> 4;              // local j (0..31)
    const int bl = tid & (BC - 1);        // local b (0..15)

    const float C = 144.26950408889634f;  // log2(e)/tau, tau = 0.01

    // ---- stage scores[b0..b0+15][0..511]*C -> sT (transposed, swizzled) ----
    {
        const int sr = tid >> 5;          // staged b-row 0..15
        const int sk = tid & 31;          // low k4 bits
        const float4* g4 = (const float4*)(scores + (size_t)(b0 + sr) * Bn);
        #pragma unroll
        for (int i = 0; i < 4; ++i) {
            const int k4 = sk + i * 32;
            float4 v = g4[k4];
            v.x *= C; v.y *= C; v.z *= C; v.w *= C;
            const int g = k4 * BC + (sr ^ (k4 & (BC - 1)));
            *(float4*)(&sT[g * 4]) = v;
        }
    }
    __syncthreads();

    const int j = j0 + jl;
    const float tj = scores[(size_t)(b0 + bl) * Bn + j] * C;
    const float4* __restrict__ trow = (const float4*)(target + (size_t)j * Bn);

    float A0 = 0.0f, A1 = 0.0f;  // sum_k sigmoid (split chains)
    float P0 = 0.0f, P1 = 0.0f;  // sum_k sigmoid * target[j,k]

    #pragma unroll 4
    for (int k4 = 0; k4 < Bn / 4; ++k4) {
        const float4 w = trow[k4];            // few distinct addrs/wave (L1/L2)
        const int g = k4 * BC + (bl ^ (k4 & (BC - 1)));
        const float4 tk = *(const float4*)(&sT[g * 4]);

        float s0 = sigterm(tj, tk.x);
        float s1 = sigterm(tj, tk.y);
        float s2 = sigterm(tj, tk.z);
        float s3 = sigterm(tj, tk.w);
        A0 += s0 + s1;
        A1 += s2 + s3;
        P0 = fmaf(s0, w.x, P0);
        P1 = fmaf(s1, w.y, P1);
        P0 = fmaf(s2, w.z, P0);
        P1 = fmaf(s3, w.w, P1);
    }
    const float A = A0 + A1;
    const float P = P0 + P1;

    // diag k=j contributes exactly 0.5 to A and P (tgt[j,j]=1):
    // sim_all = A + 0.5;  pos = P - 0.5 + target[b,j]
    const float tbj = target[(size_t)(b0 + bl) * Bn + j];
    float c  = (P - 0.5f + tbj) * tbj / (A + 0.5f);
    float tt = tbj;

    // reduce the 4 jl per wave (wave = 4 jl x 16 bl): lanes 0..15 keep sums
    c  += __shfl_down(c, 32);  c  += __shfl_down(c, 16);
    tt += __shfl_down(tt, 32); tt += __shfl_down(tt, 16);
    const int wv = tid >> 6;
    if ((tid & 63) < BC) { partC[wv * BC + bl] = c; partT[wv * BC + bl] = tt; }
    __syncthreads();

    if (tid < BC) {
        float cs = 0.0f, ts = 0.0f;
        #pragma unroll
        for (int w2 = 0; w2 < 8; ++w2) { cs += partC[w2 * BC + tid]; ts += partT[w2 * BC + tid]; }
        wsC[(size_t)blockIdx.y * Bn + b0 + tid] = cs;
        wsT[(size_t)blockIdx.y * Bn + b0 + tid] = ts;
    }
}

__global__ __launch_bounds__(512) void srap_final(
        const float* __restrict__ wsC, const float* __restrict__ wsT,
        float* __restrict__ out) {
    __shared__ float red[8];
    const int b = threadIdx.x;  // 512 threads, one per batch row
    float num = 0.0f, den = 0.0f;
    #pragma unroll
    for (int jt = 0; jt < Bn / JT; ++jt) {
        num += wsC[jt * Bn + b];
        den += wsT[jt * Bn + b];
    }
    float apb = num / den;
    for (int off = 32; off; off >>= 1) apb += __shfl_down(apb, off);
    if ((b & 63) == 0) red[b >> 6] = apb;
    __syncthreads();
    if (b == 0) {
        float s = 0.0f;
        #pragma unroll
        for (int w = 0; w < 8; ++w) s += red[w];
        out[0] = 1.0f - s * (1.0f / Bn);
    }
}

extern "C" void kernel_launch(void* const* d_in, const int* in_sizes, int n_in,
                              void* d_out, int out_size, void* d_ws, size_t ws_size,
                              hipStream_t stream) {
    const float* scores = (const float*)d_in[0];
    const float* target = (const float*)d_in[1];
    float* out = (float*)d_out;
    float* wsC = (float*)d_ws;                       // 16*512 floats
    float* wsT = wsC + (Bn / JT) * Bn;               // 16*512 floats

    srap_main<<<dim3(Bn / BC, Bn / JT), dim3(512), 0, stream>>>(scores, target, wsC, wsT);
    srap_final<<<dim3(1), dim3(512), 0, stream>>>(wsC, wsT, out);
}